// Round 6
// baseline (4633.924 us; speedup 1.0000x reference)
//
#include <hip/hip_runtime.h>
#include <hip/hip_bf16.h>
#include <math.h>

// ---------------------------------------------------------------------------
// InfNet: 2-layer GCN + Weibull epilogue.
// GEMMs: bf16x3 split as ONE pass: [Ah|Al|Ah] * [Bh;Bh;Bl] via K-wrap remap,
// with dinv[row] row-scaling fused into the epilogue (T1s = (x@W0)*dinv,
// T2s = (H1@W1)*dinv) so the aggregation hot loop has NO per-edge weight.
// Aggregations fp32, SINGLE-GENERATION COHERENT SWEEP:
//   - edges counting-sorted by (dst>>6, src>>12, dst&63): each block owns 64
//     consecutive dst nodes; per (wave, bucket) its 16 nodes' edges are one
//     contiguous range; buckets are 4096-src-row (2MB) windows.
//   - grid = 782 blocks, LDS 33KB -> 4 blocks/CU capacity: ALL blocks resident
//     from t=0, so every wave sweeps buckets 0..12 in near-lockstep without
//     any barriers -> gathers hit per-XCD L2 (round-3 showed FETCH halves;
//     round-4 showed staggered generations destroy it).
//   - accumulators in LDS (accs[64][64] float2), per-edge ds_add_f32 atomics:
//     chain-free routing by runtime node index (VGPR-indexed arrays would
//     spill; LDS computed addressing is free). Each wave owns its 16 rows
//     exclusively -> deterministic order, zero barriers.
//   - agg1 = 2 half-feature passes (512B/row windows), agg2 = 1 pass.
// (Round-5 submission failed on container infra; audited for OOB/race/hang,
//  no defect found -> resubmitted unchanged.)
// ---------------------------------------------------------------------------

typedef unsigned short ushort_t;
typedef __attribute__((ext_vector_type(8))) short bf16x8;
typedef __attribute__((ext_vector_type(4))) float f32x4;

#define NB 13            // src buckets (src>>12, 4096 rows each)
#define BSHIFT 12
#define GNODES 64        // dst nodes per block
#define KEYS_PER_G (NB * GNODES)   // 832

__device__ __forceinline__ ushort_t f2bf(float f) {
    union { float f; unsigned u; } x; x.f = f;
    unsigned r = x.u + 0x7FFF + ((x.u >> 16) & 1);   // RNE
    return (ushort_t)(r >> 16);
}
__device__ __forceinline__ float bf2f(ushort_t s) {
    union { unsigned u; float f; } x; x.u = ((unsigned)s) << 16; return x.f;
}

__device__ __forceinline__ void async_copy16(const void* gsrc, void* ldst) {
    __builtin_amdgcn_global_load_lds(
        (const __attribute__((address_space(1))) unsigned int*)gsrc,
        (__attribute__((address_space(3))) unsigned int*)ldst,
        16, 0, 0);
}

// ---------------- graph preprocessing ----------------

// count edges per key = (dst>>6)*832 + (src>>12)*64 + (dst&63)
__global__ __launch_bounds__(256) void count2_kernel(const int* __restrict__ src,
                                                     const int* __restrict__ dst,
                                                     int* __restrict__ cnt2, int E)
{
    int e = blockIdx.x * blockDim.x + threadIdx.x;
    if (e < E) {
        int d = dst[e], s = src[e];
        atomicAdd(&cnt2[(d >> 6) * KEYS_PER_G + (s >> BSHIFT) * 64 + (d & 63)], 1);
    }
}

// degree (and dinv) from pre-scan cnt2
__global__ __launch_bounds__(256) void dinv_kernel(const int* __restrict__ cnt2,
                                                   float* __restrict__ dinv, int N)
{
    int i = blockIdx.x * blockDim.x + threadIdx.x;
    if (i < N) {
        int base = (i >> 6) * KEYS_PER_G + (i & 63);
        int d = 0;
#pragma unroll
        for (int p = 0; p < NB; ++p) d += cnt2[base + p * 64];
        dinv[i] = rsqrtf((float)(d + 1));
    }
}

// generic hierarchical scan pieces (1024-block local scan)
__global__ __launch_bounds__(1024) void scan_local(const int* __restrict__ cnt,
                                                   int* __restrict__ outp,
                                                   int* __restrict__ blksum, int N)
{
    __shared__ int wsum[16];
    int tid = threadIdx.x, lane = tid & 63, wid = tid >> 6;
    int i = blockIdx.x * 1024 + tid;
    int v = (i < N) ? cnt[i] : 0;
    int s = v;
#pragma unroll
    for (int off = 1; off < 64; off <<= 1) {
        int t = __shfl_up(s, off, 64);
        if (lane >= off) s += t;
    }
    if (lane == 63) wsum[wid] = s;
    __syncthreads();
    if (tid < 16) {
        int w = wsum[tid];
#pragma unroll
        for (int off = 1; off < 16; off <<= 1) {
            int t = __shfl_up(w, off, 64);
            if (tid >= off) w += t;
        }
        wsum[tid] = w;
    }
    __syncthreads();
    int excl = s - v + (wid ? wsum[wid - 1] : 0);
    if (i < N) outp[i] = excl;
    if (tid == 0) blksum[blockIdx.x] = wsum[15];
}

__global__ __launch_bounds__(64) void scan_blk(const int* __restrict__ blksum,
                                               int* __restrict__ blkoff,
                                               int nblk, int* __restrict__ endp, int LEN)
{
    int tid = threadIdx.x;
    int v = (tid < nblk) ? blksum[tid] : 0;
    int s = v;
#pragma unroll
    for (int off = 1; off < 64; off <<= 1) {
        int t = __shfl_up(s, off, 64);
        if (tid >= off) s += t;
    }
    if (tid < nblk) blkoff[tid] = s - v;
    if (tid == nblk - 1) endp[LEN] = s;     // total = E
}

__global__ __launch_bounds__(256) void final_add(int* __restrict__ R2,
                                                 int* __restrict__ cursor2,
                                                 const int* __restrict__ bs1p,
                                                 const int* __restrict__ bo2, int LEN)
{
    int i = blockIdx.x * blockDim.x + threadIdx.x;
    if (i < LEN) {
        int r = R2[i] + bs1p[i >> 10] + bo2[i >> 20];
        R2[i] = r;
        cursor2[i] = r;
    }
}

// col[pos] = (dst&63)<<16 | src   (src < 50000 < 2^16)
__global__ __launch_bounds__(256) void scatter2_kernel(const int* __restrict__ src,
                                                       const int* __restrict__ dst,
                                                       int* __restrict__ cursor2,
                                                       int* __restrict__ col, int E)
{
    int e = blockIdx.x * blockDim.x + threadIdx.x;
    if (e < E) {
        int d = dst[e], s = src[e];
        int key = (d >> 6) * KEYS_PER_G + (s >> BSHIFT) * 64 + (d & 63);
        int pos = atomicAdd(&cursor2[key], 1);
        col[pos] = ((d & 63) << 16) | s;
    }
}

// ---------------- operand conversion (bf16 hi/lo split) ----------------

__global__ __launch_bounds__(256) void conv_x(const float* __restrict__ x,
                                              ushort_t* __restrict__ Abig,
                                              int M, int M_pad)
{
    int id = blockIdx.x * blockDim.x + threadIdx.x;
    int r = id >> 7, q = id & 127;
    if (r >= M_pad) return;
    float4 v = make_float4(0.f, 0.f, 0.f, 0.f);
    if (r < M) v = *reinterpret_cast<const float4*>(&x[(size_t)r * 512 + q * 4]);
    ushort4 h, l;
    h.x = f2bf(v.x); l.x = f2bf(v.x - bf2f(h.x));
    h.y = f2bf(v.y); l.y = f2bf(v.y - bf2f(h.y));
    h.z = f2bf(v.z); l.z = f2bf(v.z - bf2f(h.z));
    h.w = f2bf(v.w); l.w = f2bf(v.w - bf2f(h.w));
    ushort_t* rowp = Abig + (size_t)r * 1024;
    *reinterpret_cast<ushort4*>(rowp + q * 4)       = h;
    *reinterpret_cast<ushort4*>(rowp + 512 + q * 4) = l;
}

// W0bigT (256 x 1536), row n: [hi(512) | hi(512) | lo(512)] of W0[:,n].
__global__ __launch_bounds__(256) void conv_w0(const float* __restrict__ W0,
                                               ushort_t* __restrict__ BT)
{
    int id = blockIdx.x * blockDim.x + threadIdx.x;
    int k = id & 511, n = id >> 9;
    if (n >= 256) return;
    float v = W0[(size_t)k * 256 + n];
    ushort_t h = f2bf(v);
    ushort_t l = f2bf(v - bf2f(h));
    ushort_t* rowp = BT + (size_t)n * 1536;
    rowp[k] = h; rowp[512 + k] = h; rowp[1024 + k] = l;
}

// W1bigT (128 x 768), row n: [hi(256) | hi(256) | lo(256)]; plus W1col fp32.
__global__ __launch_bounds__(256) void conv_w1(const float* __restrict__ W1,
                                               ushort_t* __restrict__ BT,
                                               float* __restrict__ W1col)
{
    int id = blockIdx.x * blockDim.x + threadIdx.x;
    int k = id & 255, n = id >> 8;
    if (n >= 128) return;
    float v = W1[(size_t)k * 129 + n];
    ushort_t h = f2bf(v);
    ushort_t l = f2bf(v - bf2f(h));
    ushort_t* rowp = BT + (size_t)n * 768;
    rowp[k] = h; rowp[256 + k] = h; rowp[512 + k] = l;
    if (n == 0) W1col[k] = W1[(size_t)k * 129 + 128];
}

// ---------------- MFMA GEMM: C = (A * BT^T) * rowscale[r] ----------------
// K iterates [0, K); A's k-index wraps at kwrap (so Ah reused for the Bl band).
// 128x128 tile, BK=32, 256 thr = 4 waves (2x2 of 64x64), 16x16x32 MFMA.
__global__ __launch_bounds__(256) void gemm_bf16(const ushort_t* __restrict__ A, int lda,
                                                 const ushort_t* __restrict__ BT, int ldbt,
                                                 float* __restrict__ C, int ldc,
                                                 int M, int K, int kwrap,
                                                 const float* __restrict__ rowscale)
{
    __shared__ short As[128 * 32];
    __shared__ short Bs[128 * 32];

    int tid  = threadIdx.x;
    int w    = tid >> 6;
    int lane = tid & 63;
    int lm   = lane & 15;
    int lq   = lane >> 4;
    int bm   = blockIdx.x * 128;
    int bn   = blockIdx.y * 128;
    int wr   = (w >> 1) * 64;
    int wc   = (w & 1) * 64;

    f32x4 acc[4][4];
#pragma unroll
    for (int i = 0; i < 4; ++i)
#pragma unroll
        for (int j = 0; j < 4; ++j) acc[i][j] = (f32x4)(0.f);

    int srow = (lane >> 2);
    int scol = (lane & 3) * 16;

    for (int k0 = 0; k0 < K; k0 += 32) {
        int ka = (k0 < kwrap) ? k0 : (k0 - kwrap);   // A k-wrap (tiles never straddle)
#pragma unroll
        for (int q = 0; q < 2; ++q) {
            int r = w * 32 + q * 16 + srow;
            const char* ga = (const char*)A + ((size_t)(bm + r) * lda + ka) * 2 + scol;
            async_copy16(ga, (char*)As + (size_t)(w * 32 + q * 16) * 64);
        }
#pragma unroll
        for (int q = 0; q < 2; ++q) {
            int r = w * 32 + q * 16 + srow;
            const char* gb = (const char*)BT + ((size_t)(bn + r) * ldbt + k0) * 2 + scol;
            async_copy16(gb, (char*)Bs + (size_t)(w * 32 + q * 16) * 64);
        }
        __syncthreads();

        bf16x8 afr[4], bfr[4];
#pragma unroll
        for (int mi = 0; mi < 4; ++mi)
            afr[mi] = *reinterpret_cast<const bf16x8*>(&As[(wr + mi * 16 + lm) * 32 + lq * 8]);
#pragma unroll
        for (int ni = 0; ni < 4; ++ni)
            bfr[ni] = *reinterpret_cast<const bf16x8*>(&Bs[(wc + ni * 16 + lm) * 32 + lq * 8]);
#pragma unroll
        for (int mi = 0; mi < 4; ++mi)
#pragma unroll
            for (int ni = 0; ni < 4; ++ni)
                acc[mi][ni] = __builtin_amdgcn_mfma_f32_16x16x32_bf16(
                    afr[mi], bfr[ni], acc[mi][ni], 0, 0, 0);
        __syncthreads();
    }

#pragma unroll
    for (int mi = 0; mi < 4; ++mi) {
#pragma unroll
        for (int ni = 0; ni < 4; ++ni) {
            int rbase = bm + wr + mi * 16 + lq * 4;
            int cc    = bn + wc + ni * 16 + lm;
#pragma unroll
            for (int e = 0; e < 4; ++e) {
                int r = rbase + e;
                if (r < M) C[(size_t)r * ldc + cc] = acc[mi][ni][e] * rowscale[r];
            }
        }
    }
}

// ---------------- fused pieces ----------------

__device__ __forceinline__ float softplus_f(float x)
{
    return fmaxf(x, 0.f) + log1pf(expf(-fabsf(x)));
}

// layer-1 aggregation + softplus -> H1big bf16 [hi(256) | lo(256)];
// half-feature pass (pass=0: cols 0..127, pass=1: 128..255).
// out = softplus(dinv[dst] * (sum_nbr T1s[src] + T1s[dst])), T1s pre-scaled.
// kappa partial dot accumulated across the two passes into T2k; pass 1
// finishes with the dinv[node] source-scale (T2k becomes T2ks).
__global__ __launch_bounds__(256) void agg1_kernel(const float* __restrict__ T1s,
                                                   const float* __restrict__ dinv,
                                                   const int* __restrict__ R2,
                                                   const int* __restrict__ col,
                                                   const float* __restrict__ W1col,
                                                   ushort_t* __restrict__ H1big,
                                                   float* __restrict__ T2k,
                                                   int N, int pass)
{
    __shared__ float2 accs[64][64];
    int g    = blockIdx.x;
    int w    = threadIdx.x >> 6;
    int lane = threadIdx.x & 63;

#pragma unroll
    for (int q = 0; q < 16; ++q)
        accs[w * 16 + q][lane] = make_float2(0.f, 0.f);
    // each wave owns rows [w*16, w*16+16) exclusively -> no barriers anywhere

    const float* gbase = T1s + pass * 128 + lane * 2;
    int kb = g * KEYS_PER_G + w * 16;

    for (int p = 0; p < NB; ++p) {
        int A = R2[kb + p * 64];
        int B = R2[kb + p * 64 + 16];
        for (int i = A; i < B; i += 8) {
            int cnt = B - i;          // wave-uniform
            int mm[8];
#pragma unroll
            for (int j = 0; j < 8; ++j) mm[j] = col[i + j];   // uniform, speculative ok
            float2 v[8];
#pragma unroll
            for (int j = 0; j < 8; ++j)
                v[j] = *reinterpret_cast<const float2*>(gbase + (size_t)(mm[j] & 0xffff) * 256);
#pragma unroll
            for (int j = 0; j < 8; ++j) {
                if (j < cnt) {
                    int loc = mm[j] >> 16;
                    atomicAdd(&accs[loc][lane].x, v[j].x);   // ds_add_f32, chain-free
                    atomicAdd(&accs[loc][lane].y, v[j].y);
                }
            }
        }
    }

#pragma unroll
    for (int q = 0; q < 16; ++q) {
        int local = w * 16 + q;
        int node  = g * 64 + local;
        if (node >= N) continue;
        float di = dinv[node];
        float2 a = accs[local][lane];
        float2 self = *reinterpret_cast<const float2*>(
            T1s + (size_t)node * 256 + pass * 128 + lane * 2);
        float ox = softplus_f((a.x + self.x) * di);
        float oy = softplus_f((a.y + self.y) * di);
        ushort_t hx = f2bf(ox), lx = f2bf(ox - bf2f(hx));
        ushort_t hy = f2bf(oy), ly = f2bf(oy - bf2f(hy));
        ushort_t* rowp = H1big + (size_t)node * 512 + pass * 128 + lane * 2;
        *reinterpret_cast<ushort2*>(rowp)       = make_ushort2(hx, hy);
        *reinterpret_cast<ushort2*>(rowp + 256) = make_ushort2(lx, ly);

        float wx = W1col[pass * 128 + lane * 2];
        float wy = W1col[pass * 128 + lane * 2 + 1];
        float tk = ox * wx + oy * wy;
#pragma unroll
        for (int off = 32; off > 0; off >>= 1)
            tk += __shfl_down(tk, off, 64);
        if (lane == 0) {
            if (pass == 0) T2k[node] = tk;
            else           T2k[node] = (T2k[node] + tk) * di;   // -> T2ks
        }
    }
}

// layer-2 aggregation + softplus + Weibull epilogue, single pass.
// sp = softplus(di*(sum T2s[src] + T2s[dst])); ak = di*(sum T2ks[src] + T2ks[dst]).
__global__ __launch_bounds__(256) void agg2_kernel(const float* __restrict__ T2s,
                                                   const float* __restrict__ T2k,
                                                   const float* __restrict__ dinv,
                                                   const int* __restrict__ R2,
                                                   const int* __restrict__ col,
                                                   float* __restrict__ z_out,
                                                   float* __restrict__ lbd_out,
                                                   float* __restrict__ kap_out, int N)
{
    __shared__ float2 accs[64][64];
    __shared__ float  kacc[64];
    int g    = blockIdx.x;
    int w    = threadIdx.x >> 6;
    int lane = threadIdx.x & 63;

#pragma unroll
    for (int q = 0; q < 16; ++q)
        accs[w * 16 + q][lane] = make_float2(0.f, 0.f);
    if (lane < 16) kacc[w * 16 + lane] = 0.f;

    const float* gbase = T2s + lane * 2;
    int kb = g * KEYS_PER_G + w * 16;

    for (int p = 0; p < NB; ++p) {
        int A = R2[kb + p * 64];
        int B = R2[kb + p * 64 + 16];
        for (int i = A; i < B; i += 8) {
            int cnt = B - i;
            int mm[8];
#pragma unroll
            for (int j = 0; j < 8; ++j) mm[j] = col[i + j];
            float2 v[8]; float t[8];
#pragma unroll
            for (int j = 0; j < 8; ++j) {
                int src = mm[j] & 0xffff;
                v[j] = *reinterpret_cast<const float2*>(gbase + (size_t)src * 128);
                t[j] = T2k[src];                         // broadcast line
            }
#pragma unroll
            for (int j = 0; j < 8; ++j) {
                if (j < cnt) {
                    int loc = mm[j] >> 16;
                    atomicAdd(&accs[loc][lane].x, v[j].x);
                    atomicAdd(&accs[loc][lane].y, v[j].y);
                    if (lane == 0) atomicAdd(&kacc[loc], t[j]);
                }
            }
        }
    }

#pragma unroll
    for (int q = 0; q < 16; ++q) {
        int local = w * 16 + q;
        int node  = g * 64 + local;
        if (node >= N) continue;
        float di = dinv[node];
        float2 a = accs[local][lane];
        float2 self = *reinterpret_cast<const float2*>(T2s + (size_t)node * 128 + lane * 2);
        float2 sp;
        sp.x = softplus_f((a.x + self.x) * di);
        sp.y = softplus_f((a.y + self.y) * di);

        float ak = (kacc[local] + T2k[node]) * di;
        float kv = softplus_f(ak) + 0.1f;
        float gm = expf(lgammaf(1.0f + 1.0f / kv));
        if (lane == 0) kap_out[node] = kv;

        size_t o = (size_t)node * 128 + lane * 2;
        *reinterpret_cast<float2*>(&lbd_out[o]) = sp;
        *reinterpret_cast<float2*>(&z_out[o])   = make_float2(sp.x * gm, sp.y * gm);
    }
}

extern "C" void kernel_launch(void* const* d_in, const int* in_sizes, int n_in,
                              void* d_out, int out_size, void* d_ws, size_t ws_size,
                              hipStream_t stream)
{
    const float* x  = (const float*)d_in[0];
    const int*   ei = (const int*)d_in[1];
    const float* W0 = (const float*)d_in[2];
    const float* W1 = (const float*)d_in[3];

    const int N = in_sizes[0] / 512;      // 50000
    const int E = in_sizes[1] / 2;        // 1600000
    const int* src = ei;
    const int* dst = ei + E;

    const int mblocks = (N + 127) / 128;   // 391
    const int M_pad   = mblocks * 128;     // 50048
    const int NG      = (N + 63) / 64;     // 782 node groups
    const int LEN     = NG * KEYS_PER_G;   // 650,624
    const int nblk1   = (LEN + 1023) / 1024;   // 636
    const int nblk2   = (nblk1 + 1023) / 1024; // 1

    char* w = (char*)d_ws;
    size_t off = 0;
    auto take = [&](size_t bytes) -> void* {
        void* p = (void*)(w + off);
        off = (off + bytes + 255) & ~(size_t)255;
        return p;
    };
    int*      R2     = (int*)take((size_t)(LEN + 1) * 4);
    float*    dinv   = (float*)take((size_t)N * 4);
    int*      col    = (int*)take((size_t)(E + 8) * 4);
    int*      bs1    = (int*)take((size_t)1280 * 4);
    int*      bs1p   = (int*)take((size_t)1280 * 4);
    int*      bs2    = (int*)take((size_t)64 * 4);
    int*      bo2    = (int*)take((size_t)64 * 4);
    ushort_t* W0bigT = (ushort_t*)take((size_t)256 * 1536 * 2);
    ushort_t* W1bigT = (ushort_t*)take((size_t)128 * 768 * 2);
    float*    W1col  = (float*)take((size_t)256 * 4);
    float*    T2k    = (float*)take((size_t)N * 4);
    float*    T1     = (float*)take((size_t)N * 256 * 4);   // 51.2 MB (T1s)
    float*    T2     = T1;                 // T1s dead after agg1; reuse (T2s)
    ushort_t* Abig   = (ushort_t*)take((size_t)M_pad * 1024 * 2);   // 102.5 MB
    ushort_t* H1big  = Abig;               // alias: Abig dead after gemm1

    // cnt2/cursor2 are dead before GEMM1 writes T1 -> alias into T1's space.
    int* cnt2    = (int*)T1;
    int* cursor2 = (int*)((char*)T1 + (size_t)16 * 1024 * 1024);

    float* z_out   = (float*)d_out;
    float* lbd_out = z_out + (size_t)N * 128;
    float* kap_out = lbd_out + (size_t)N * 128;

    // ---- build group/bucket-sorted CSR ----
    hipMemsetAsync(cnt2, 0, (size_t)LEN * 4, stream);
    hipMemsetAsync(col + E, 0, 32, stream);   // pad for speculative reads
    count2_kernel<<<(E + 255) / 256, 256, 0, stream>>>(src, dst, cnt2, E);
    dinv_kernel<<<(N + 255) / 256, 256, 0, stream>>>(cnt2, dinv, N);
    scan_local<<<nblk1, 1024, 0, stream>>>(cnt2, R2, bs1, LEN);
    scan_local<<<nblk2, 1024, 0, stream>>>(bs1, bs1p, bs2, nblk1);
    scan_blk<<<1, 64, 0, stream>>>(bs2, bo2, nblk2, R2, LEN);   // R2[LEN]=E
    final_add<<<(LEN + 255) / 256, 256, 0, stream>>>(R2, cursor2, bs1p, bo2, LEN);
    scatter2_kernel<<<(E + 255) / 256, 256, 0, stream>>>(src, dst, cursor2, col, E);

    conv_x<<<(M_pad * 128) / 256, 256, 0, stream>>>(x, Abig, N, M_pad);
    conv_w0<<<(256 * 512) / 256, 256, 0, stream>>>(W0, W0bigT);
    conv_w1<<<(128 * 256) / 256, 256, 0, stream>>>(W1, W1bigT, W1col);

    // GEMM1: T1s = (x @ W0) * dinv[row]  (bf16x3 one pass, K=1536, A wraps at 1024)
    dim3 g1(mblocks, 2);
    gemm_bf16<<<g1, 256, 0, stream>>>(Abig, 1024, W0bigT, 1536, T1, 256, N, 1536, 1024, dinv);

    // agg1: 2 half-feature coherent sweeps (all 782 blocks resident).
    agg1_kernel<<<NG, 256, 0, stream>>>(T1, dinv, R2, col, W1col, H1big, T2k, N, 0);
    agg1_kernel<<<NG, 256, 0, stream>>>(T1, dinv, R2, col, W1col, H1big, T2k, N, 1);

    // GEMM2: T2s = (H1 @ W1main) * dinv[row]  (K=768, A wraps at 512)
    dim3 g2(mblocks, 1);
    gemm_bf16<<<g2, 256, 0, stream>>>(H1big, 512, W1bigT, 768, T2, 128, N, 768, 512, dinv);

    agg2_kernel<<<NG, 256, 0, stream>>>(T2, T2k, dinv, R2, col,
                                        z_out, lbd_out, kap_out, N);
}

// Round 7
// 833.976 us; speedup vs baseline: 5.5564x; 5.5564x over previous
//
#include <hip/hip_runtime.h>
#include <hip/hip_bf16.h>
#include <math.h>

// ---------------------------------------------------------------------------
// InfNet: 2-layer GCN + Weibull epilogue.
// GEMMs: bf16x3 split as ONE pass: [Ah|Al|Ah] * [Bh;Bh;Bl] via K-wrap remap,
// with dinv[row] scaling fused into the GEMM epilogue (T1s=(x@W0)*dinv,
// T2s=(H1@W1)*dinv; T2k prescaled by dinv) -> agg hot loops have NO per-edge
// weight gather and a minimal chain: col[e] -> row gather -> add.
// Aggregations fp32, wave-per-node (r1 structure: best verified 820us;
// r3/r6 showed FETCH reduction doesn't pay -- the limiter is L2 request
// rate, so fewer line-requests per edge is the lever, not locality).
// ---------------------------------------------------------------------------

typedef unsigned short ushort_t;
typedef __attribute__((ext_vector_type(8))) short bf16x8;
typedef __attribute__((ext_vector_type(4))) float f32x4;

__device__ __forceinline__ ushort_t f2bf(float f) {
    union { float f; unsigned u; } x; x.f = f;
    unsigned r = x.u + 0x7FFF + ((x.u >> 16) & 1);   // RNE
    return (ushort_t)(r >> 16);
}
__device__ __forceinline__ float bf2f(ushort_t s) {
    union { unsigned u; float f; } x; x.u = ((unsigned)s) << 16; return x.f;
}

__device__ __forceinline__ void async_copy16(const void* gsrc, void* ldst) {
    __builtin_amdgcn_global_load_lds(
        (const __attribute__((address_space(1))) unsigned int*)gsrc,
        (__attribute__((address_space(3))) unsigned int*)ldst,
        16, 0, 0);
}

// ---------------- graph preprocessing (plain CSR, r1 version) ----------------

__global__ __launch_bounds__(256) void count_kernel(const int* __restrict__ dst,
                                                    int* __restrict__ cnt, int E)
{
    int e = blockIdx.x * blockDim.x + threadIdx.x;
    if (e < E) atomicAdd(&cnt[dst[e]], 1);
}

__global__ __launch_bounds__(1024) void scan_local(const int* __restrict__ cnt,
                                                   int* __restrict__ rowptr,
                                                   float* __restrict__ dinv,
                                                   int* __restrict__ blksum, int N)
{
    __shared__ int wsum[16];
    int tid = threadIdx.x, lane = tid & 63, wid = tid >> 6;
    int i = blockIdx.x * 1024 + tid;
    int v = (i < N) ? cnt[i] : 0;
    if (i < N) dinv[i] = rsqrtf((float)(v + 1));
    int s = v;
#pragma unroll
    for (int off = 1; off < 64; off <<= 1) {
        int t = __shfl_up(s, off, 64);
        if (lane >= off) s += t;
    }
    if (lane == 63) wsum[wid] = s;
    __syncthreads();
    if (tid < 16) {
        int w = wsum[tid];
#pragma unroll
        for (int off = 1; off < 16; off <<= 1) {
            int t = __shfl_up(w, off, 64);
            if (tid >= off) w += t;
        }
        wsum[tid] = w;
    }
    __syncthreads();
    int excl = s - v + (wid ? wsum[wid - 1] : 0);
    if (i < N) rowptr[i] = excl;
    if (tid == 0) blksum[blockIdx.x] = wsum[15];
}

__global__ __launch_bounds__(64) void scan_blk(const int* __restrict__ blksum,
                                               int* __restrict__ blkoff,
                                               int nblk, int* __restrict__ rowptr, int N)
{
    int tid = threadIdx.x;
    int v = (tid < nblk) ? blksum[tid] : 0;
    int s = v;
#pragma unroll
    for (int off = 1; off < 64; off <<= 1) {
        int t = __shfl_up(s, off, 64);
        if (tid >= off) s += t;
    }
    if (tid < nblk) blkoff[tid] = s - v;
    if (tid == nblk - 1) rowptr[N] = s;
}

__global__ __launch_bounds__(256) void scan_add(int* __restrict__ rowptr,
                                                int* __restrict__ cursor,
                                                const int* __restrict__ blkoff, int N)
{
    int i = blockIdx.x * blockDim.x + threadIdx.x;
    if (i < N) {
        int r = rowptr[i] + blkoff[i >> 10];
        rowptr[i] = r;
        cursor[i] = r;
    }
}

__global__ __launch_bounds__(256) void scatter_kernel(const int* __restrict__ src,
                                                      const int* __restrict__ dst,
                                                      int* __restrict__ cursor,
                                                      int* __restrict__ col, int E)
{
    int e = blockIdx.x * blockDim.x + threadIdx.x;
    if (e < E) {
        int d = dst[e];
        int pos = atomicAdd(&cursor[d], 1);
        col[pos] = src[e];
    }
}

// ---------------- operand conversion (bf16 hi/lo split) ----------------

__global__ __launch_bounds__(256) void conv_x(const float* __restrict__ x,
                                              ushort_t* __restrict__ Abig,
                                              int M, int M_pad)
{
    int id = blockIdx.x * blockDim.x + threadIdx.x;
    int r = id >> 7, q = id & 127;
    if (r >= M_pad) return;
    float4 v = make_float4(0.f, 0.f, 0.f, 0.f);
    if (r < M) v = *reinterpret_cast<const float4*>(&x[(size_t)r * 512 + q * 4]);
    ushort4 h, l;
    h.x = f2bf(v.x); l.x = f2bf(v.x - bf2f(h.x));
    h.y = f2bf(v.y); l.y = f2bf(v.y - bf2f(h.y));
    h.z = f2bf(v.z); l.z = f2bf(v.z - bf2f(h.z));
    h.w = f2bf(v.w); l.w = f2bf(v.w - bf2f(h.w));
    ushort_t* rowp = Abig + (size_t)r * 1024;
    *reinterpret_cast<ushort4*>(rowp + q * 4)       = h;
    *reinterpret_cast<ushort4*>(rowp + 512 + q * 4) = l;
}

// W0bigT (256 x 1536), row n: [hi(512) | hi(512) | lo(512)] of W0[:,n].
__global__ __launch_bounds__(256) void conv_w0(const float* __restrict__ W0,
                                               ushort_t* __restrict__ BT)
{
    int id = blockIdx.x * blockDim.x + threadIdx.x;
    int k = id & 511, n = id >> 9;
    if (n >= 256) return;
    float v = W0[(size_t)k * 256 + n];
    ushort_t h = f2bf(v);
    ushort_t l = f2bf(v - bf2f(h));
    ushort_t* rowp = BT + (size_t)n * 1536;
    rowp[k] = h; rowp[512 + k] = h; rowp[1024 + k] = l;
}

// W1bigT (128 x 768), row n: [hi(256) | hi(256) | lo(256)]; plus W1col fp32.
__global__ __launch_bounds__(256) void conv_w1(const float* __restrict__ W1,
                                               ushort_t* __restrict__ BT,
                                               float* __restrict__ W1col)
{
    int id = blockIdx.x * blockDim.x + threadIdx.x;
    int k = id & 255, n = id >> 8;
    if (n >= 128) return;
    float v = W1[(size_t)k * 129 + n];
    ushort_t h = f2bf(v);
    ushort_t l = f2bf(v - bf2f(h));
    ushort_t* rowp = BT + (size_t)n * 768;
    rowp[k] = h; rowp[256 + k] = h; rowp[512 + k] = l;
    if (n == 0) W1col[k] = W1[(size_t)k * 129 + 128];
}

// ---------------- MFMA GEMM: C = (A * BT^T) * rowscale[r] ----------------
// K iterates [0, K); A's k-index wraps at kwrap (so Ah reused for the Bl band).
// 128x128 tile, BK=32, 256 thr = 4 waves (2x2 of 64x64), 16x16x32 MFMA.
__global__ __launch_bounds__(256) void gemm_bf16(const ushort_t* __restrict__ A, int lda,
                                                 const ushort_t* __restrict__ BT, int ldbt,
                                                 float* __restrict__ C, int ldc,
                                                 int M, int K, int kwrap,
                                                 const float* __restrict__ rowscale)
{
    __shared__ short As[128 * 32];
    __shared__ short Bs[128 * 32];

    int tid  = threadIdx.x;
    int w    = tid >> 6;
    int lane = tid & 63;
    int lm   = lane & 15;
    int lq   = lane >> 4;
    int bm   = blockIdx.x * 128;
    int bn   = blockIdx.y * 128;
    int wr   = (w >> 1) * 64;
    int wc   = (w & 1) * 64;

    f32x4 acc[4][4];
#pragma unroll
    for (int i = 0; i < 4; ++i)
#pragma unroll
        for (int j = 0; j < 4; ++j) acc[i][j] = (f32x4)(0.f);

    int srow = (lane >> 2);
    int scol = (lane & 3) * 16;

    for (int k0 = 0; k0 < K; k0 += 32) {
        int ka = (k0 < kwrap) ? k0 : (k0 - kwrap);   // A k-wrap (tiles never straddle)
#pragma unroll
        for (int q = 0; q < 2; ++q) {
            int r = w * 32 + q * 16 + srow;
            const char* ga = (const char*)A + ((size_t)(bm + r) * lda + ka) * 2 + scol;
            async_copy16(ga, (char*)As + (size_t)(w * 32 + q * 16) * 64);
        }
#pragma unroll
        for (int q = 0; q < 2; ++q) {
            int r = w * 32 + q * 16 + srow;
            const char* gb = (const char*)BT + ((size_t)(bn + r) * ldbt + k0) * 2 + scol;
            async_copy16(gb, (char*)Bs + (size_t)(w * 32 + q * 16) * 64);
        }
        __syncthreads();

        bf16x8 afr[4], bfr[4];
#pragma unroll
        for (int mi = 0; mi < 4; ++mi)
            afr[mi] = *reinterpret_cast<const bf16x8*>(&As[(wr + mi * 16 + lm) * 32 + lq * 8]);
#pragma unroll
        for (int ni = 0; ni < 4; ++ni)
            bfr[ni] = *reinterpret_cast<const bf16x8*>(&Bs[(wc + ni * 16 + lm) * 32 + lq * 8]);
#pragma unroll
        for (int mi = 0; mi < 4; ++mi)
#pragma unroll
            for (int ni = 0; ni < 4; ++ni)
                acc[mi][ni] = __builtin_amdgcn_mfma_f32_16x16x32_bf16(
                    afr[mi], bfr[ni], acc[mi][ni], 0, 0, 0);
        __syncthreads();
    }

#pragma unroll
    for (int mi = 0; mi < 4; ++mi) {
#pragma unroll
        for (int ni = 0; ni < 4; ++ni) {
            int rbase = bm + wr + mi * 16 + lq * 4;
            int cc    = bn + wc + ni * 16 + lm;
#pragma unroll
            for (int e = 0; e < 4; ++e) {
                int r = rbase + e;
                if (r < M) C[(size_t)r * ldc + cc] = acc[mi][ni][e] * rowscale[r];
            }
        }
    }
}

// ---------------- fused pieces ----------------

__device__ __forceinline__ float softplus_f(float x)
{
    return fmaxf(x, 0.f) + log1pf(expf(-fabsf(x)));
}

__device__ __forceinline__ void add4(float4& a, const float4& v)
{
    a.x += v.x; a.y += v.y; a.z += v.z; a.w += v.w;
}

__device__ __forceinline__ void add2(float2& a, const float2& v)
{
    a.x += v.x; a.y += v.y;
}

// layer-1 aggregation + softplus -> H1big bf16 [hi(256) | lo(256)] per node;
// fused kappa column dot (T2ks = dinv * (H1 . W1col)).
// Wave-per-node; rows prescaled by dinv[src] in the GEMM epilogue, so the
// hot loop is col[e] -> gather -> add (no weight gather, no multiply).
__global__ __launch_bounds__(256) void agg1_kernel(const float* __restrict__ T1s,
                                                   const float* __restrict__ dinv,
                                                   const int* __restrict__ rowptr,
                                                   const int* __restrict__ col,
                                                   const float* __restrict__ W1col,
                                                   ushort_t* __restrict__ H1big,
                                                   float* __restrict__ T2k, int N)
{
    int wslot = __builtin_amdgcn_readfirstlane(threadIdx.x >> 6);  // wave-uniform
    int node  = blockIdx.x * 4 + wslot;
    if (node >= N) return;
    int lane = threadIdx.x & 63;
    float di = dinv[node];
    int beg = rowptr[node], end = rowptr[node + 1];

    float4 a0 = make_float4(0.f, 0.f, 0.f, 0.f);
    float4 a1 = a0, a2 = a0, a3 = a0;

    const float* Trow = T1s + (size_t)lane * 4;   // per-lane column offset

    int e = beg;
    for (; e + 4 <= end; e += 4) {
        int s0 = col[e], s1 = col[e + 1], s2 = col[e + 2], s3 = col[e + 3];
        float4 v0 = *reinterpret_cast<const float4*>(Trow + (size_t)s0 * 256);
        float4 v1 = *reinterpret_cast<const float4*>(Trow + (size_t)s1 * 256);
        float4 v2 = *reinterpret_cast<const float4*>(Trow + (size_t)s2 * 256);
        float4 v3 = *reinterpret_cast<const float4*>(Trow + (size_t)s3 * 256);
        add4(a0, v0); add4(a1, v1); add4(a2, v2); add4(a3, v3);
    }
    for (; e < end; ++e) {
        int s = col[e];
        float4 v = *reinterpret_cast<const float4*>(Trow + (size_t)s * 256);
        add4(a0, v);
    }

    float4 self = *reinterpret_cast<const float4*>(Trow + (size_t)node * 256);
    float4 o;
    o.x = softplus_f((a0.x + a1.x + a2.x + a3.x + self.x) * di);
    o.y = softplus_f((a0.y + a1.y + a2.y + a3.y + self.y) * di);
    o.z = softplus_f((a0.z + a1.z + a2.z + a3.z + self.z) * di);
    o.w = softplus_f((a0.w + a1.w + a2.w + a3.w + self.w) * di);

    ushort4 h, l;
    h.x = f2bf(o.x); l.x = f2bf(o.x - bf2f(h.x));
    h.y = f2bf(o.y); l.y = f2bf(o.y - bf2f(h.y));
    h.z = f2bf(o.z); l.z = f2bf(o.z - bf2f(h.z));
    h.w = f2bf(o.w); l.w = f2bf(o.w - bf2f(h.w));
    ushort_t* rowp = H1big + (size_t)node * 512;
    *reinterpret_cast<ushort4*>(rowp + lane * 4)       = h;
    *reinterpret_cast<ushort4*>(rowp + 256 + lane * 4) = l;

    // fused kappa column, prescaled: T2ks[node] = dinv[node] * (H1[node,:].W1col)
    float4 wv = *reinterpret_cast<const float4*>(&W1col[lane * 4]);
    float tk = o.x * wv.x + o.y * wv.y + o.z * wv.z + o.w * wv.w;
#pragma unroll
    for (int off = 32; off > 0; off >>= 1)
        tk += __shfl_down(tk, off, 64);
    if (lane == 0) T2k[node] = tk * di;
}

// layer-2 aggregation + softplus + Weibull epilogue. Wave-per-node; rows and
// T2k prescaled by dinv[src], so per edge: gather + add, T2k broadcast + add.
__global__ __launch_bounds__(256) void agg2_kernel(const float* __restrict__ T2s,
                                                   const float* __restrict__ T2k,
                                                   const float* __restrict__ dinv,
                                                   const int* __restrict__ rowptr,
                                                   const int* __restrict__ col,
                                                   float* __restrict__ z_out,
                                                   float* __restrict__ lbd_out,
                                                   float* __restrict__ kap_out, int N)
{
    int wslot = __builtin_amdgcn_readfirstlane(threadIdx.x >> 6);  // wave-uniform
    int node  = blockIdx.x * 4 + wslot;
    if (node >= N) return;
    int lane = threadIdx.x & 63;
    float di = dinv[node];
    int beg = rowptr[node], end = rowptr[node + 1];

    float2 a0 = make_float2(0.f, 0.f);
    float2 a1 = a0, a2 = a0, a3 = a0;
    float k0 = 0.f, k1 = 0.f, k2 = 0.f, k3 = 0.f;

    const float* Trow = T2s + (size_t)lane * 2;

    int e = beg;
    for (; e + 4 <= end; e += 4) {
        int s0 = col[e], s1 = col[e + 1], s2 = col[e + 2], s3 = col[e + 3];
        k0 += T2k[s0]; k1 += T2k[s1]; k2 += T2k[s2]; k3 += T2k[s3];
        float2 v0 = *reinterpret_cast<const float2*>(Trow + (size_t)s0 * 128);
        float2 v1 = *reinterpret_cast<const float2*>(Trow + (size_t)s1 * 128);
        float2 v2 = *reinterpret_cast<const float2*>(Trow + (size_t)s2 * 128);
        float2 v3 = *reinterpret_cast<const float2*>(Trow + (size_t)s3 * 128);
        add2(a0, v0); add2(a1, v1); add2(a2, v2); add2(a3, v3);
    }
    for (; e < end; ++e) {
        int s = col[e];
        k0 += T2k[s];
        float2 v = *reinterpret_cast<const float2*>(Trow + (size_t)s * 128);
        add2(a0, v);
    }

    float2 self = *reinterpret_cast<const float2*>(Trow + (size_t)node * 128);
    float2 sp;
    sp.x = softplus_f((a0.x + a1.x + a2.x + a3.x + self.x) * di);
    sp.y = softplus_f((a0.y + a1.y + a2.y + a3.y + self.y) * di);

    float ak = ((k0 + k1 + k2 + k3) + T2k[node]) * di;
    float kv = softplus_f(ak) + 0.1f;
    float g  = expf(lgammaf(1.0f + 1.0f / kv));
    if (lane == 0) kap_out[node] = kv;

    size_t o = (size_t)node * 128 + lane * 2;
    float2 zv = make_float2(sp.x * g, sp.y * g);
    *reinterpret_cast<float2*>(&lbd_out[o]) = sp;
    *reinterpret_cast<float2*>(&z_out[o])   = zv;
}

extern "C" void kernel_launch(void* const* d_in, const int* in_sizes, int n_in,
                              void* d_out, int out_size, void* d_ws, size_t ws_size,
                              hipStream_t stream)
{
    const float* x  = (const float*)d_in[0];
    const int*   ei = (const int*)d_in[1];
    const float* W0 = (const float*)d_in[2];
    const float* W1 = (const float*)d_in[3];

    const int N = in_sizes[0] / 512;      // 50000
    const int E = in_sizes[1] / 2;        // 1600000
    const int* src = ei;
    const int* dst = ei + E;

    const int mblocks = (N + 127) / 128;   // 391
    const int M_pad   = mblocks * 128;     // 50048
    const int nchunk  = (N + 1023) / 1024; // 49

    char* w = (char*)d_ws;
    size_t off = 0;
    auto take = [&](size_t bytes) -> void* {
        void* p = (void*)(w + off);
        off = (off + bytes + 255) & ~(size_t)255;
        return p;
    };
    int*      cnt    = (int*)take((size_t)N * 4);
    int*      rowptr = (int*)take((size_t)(N + 1) * 4);
    int*      cursor = (int*)take((size_t)N * 4);
    float*    dinv   = (float*)take((size_t)N * 4);
    int*      col    = (int*)take((size_t)E * 4);
    int*      blksum = (int*)take(64 * 4);
    int*      blkoff = (int*)take(64 * 4);
    ushort_t* W0bigT = (ushort_t*)take((size_t)256 * 1536 * 2);
    ushort_t* W1bigT = (ushort_t*)take((size_t)128 * 768 * 2);
    float*    W1col  = (float*)take((size_t)256 * 4);
    float*    T2k    = (float*)take((size_t)N * 4);
    float*    T1     = (float*)take((size_t)N * 256 * 4);   // T1s (prescaled)
    float*    T2     = T1;                 // T1s dead after agg1; reuse (T2s)
    ushort_t* Abig   = (ushort_t*)take((size_t)M_pad * 1024 * 2);   // 102.5 MB
    ushort_t* H1big  = Abig;               // alias: Abig dead after gemm1

    float* z_out   = (float*)d_out;
    float* lbd_out = z_out + (size_t)N * 128;
    float* kap_out = lbd_out + (size_t)N * 128;

    hipMemsetAsync(cnt, 0, (size_t)N * 4, stream);
    count_kernel<<<(E + 255) / 256, 256, 0, stream>>>(dst, cnt, E);
    scan_local<<<nchunk, 1024, 0, stream>>>(cnt, rowptr, dinv, blksum, N);
    scan_blk<<<1, 64, 0, stream>>>(blksum, blkoff, nchunk, rowptr, N);
    scan_add<<<(N + 255) / 256, 256, 0, stream>>>(rowptr, cursor, blkoff, N);
    scatter_kernel<<<(E + 255) / 256, 256, 0, stream>>>(src, dst, cursor, col, E);

    conv_x<<<(M_pad * 128) / 256, 256, 0, stream>>>(x, Abig, N, M_pad);
    conv_w0<<<(256 * 512) / 256, 256, 0, stream>>>(W0, W0bigT);
    conv_w1<<<(128 * 256) / 256, 256, 0, stream>>>(W1, W1bigT, W1col);

    // GEMM1: T1s = (x @ W0) * dinv[row]  (bf16x3 one pass, K=1536, A wraps at 1024)
    dim3 g1(mblocks, 2);
    gemm_bf16<<<g1, 256, 0, stream>>>(Abig, 1024, W0bigT, 1536, T1, 256, N, 1536, 1024, dinv);

    // agg1: wave-per-node (4 nodes per block), fused prescaled kappa column.
    agg1_kernel<<<(N + 3) / 4, 256, 0, stream>>>(T1, dinv, rowptr, col, W1col, H1big, T2k, N);

    // GEMM2: T2s = (H1 @ W1main) * dinv[row]  (K=768, A wraps at 512)
    dim3 g2(mblocks, 1);
    gemm_bf16<<<g2, 256, 0, stream>>>(H1big, 512, W1bigT, 768, T2, 128, N, 768, 512, dinv);

    agg2_kernel<<<(N + 3) / 4, 256, 0, stream>>>(T2, T2k, dinv, rowptr, col,
                                                 z_out, lbd_out, kap_out, N);
}